// Round 2
// 411.211 us; speedup vs baseline: 1.2076x; 1.2076x over previous
//
#include <hip/hip_runtime.h>

#define NN 100000
#define NE 1600000
#define DD 64
#define NB1 391    // ceil(NN/256)
#define NGRP 6250  // NN/16
#define NBGRU 1563 // ceil(NGRP/4)

typedef __attribute__((ext_vector_type(8))) short short8_t;
typedef __attribute__((ext_vector_type(4))) float f32x4;

__device__ __forceinline__ float fsig(float x) {
    return __fdividef(1.0f, 1.0f + __expf(-x));
}
__device__ __forceinline__ float ftanh(float x) {
    return __fdividef(2.0f, 1.0f + __expf(-2.0f * x)) - 1.0f;
}
__device__ __forceinline__ unsigned int bf16rne(float a) {
    unsigned int u = __float_as_uint(a);
    return (u + 0x7fffu + ((u >> 16) & 1u)) >> 16;
}
__device__ __forceinline__ short8_t pack8(float4 a, float4 b) {
    short8_t r;
    r[0] = (short)bf16rne(a.x); r[1] = (short)bf16rne(a.y);
    r[2] = (short)bf16rne(a.z); r[3] = (short)bf16rne(a.w);
    r[4] = (short)bf16rne(b.x); r[5] = (short)bf16rne(b.y);
    r[6] = (short)bf16rne(b.z); r[7] = (short)bf16rne(b.w);
    return r;
}

// ---- Sort phase: build CSR (edges grouped by dst) -----------------------
// deg/cursor are 400KB -> L2-resident atomics; total atomic count 3.2M.

__global__ __launch_bounds__(256) void hist_k(const int* __restrict__ dst,
                                              unsigned* __restrict__ deg) {
    const int e = blockIdx.x * 256 + threadIdx.x;   // grid covers NE exactly
    atomicAdd(&deg[dst[e]], 1u);
}

__global__ __launch_bounds__(256) void scan1_k(const unsigned* __restrict__ deg,
                                               unsigned* __restrict__ part,
                                               unsigned* __restrict__ bsum) {
    __shared__ unsigned s[256];
    const int t = threadIdx.x;
    const int i = blockIdx.x * 256 + t;
    const unsigned v = (i < NN) ? deg[i] : 0u;
    s[t] = v;
    __syncthreads();
    for (int off = 1; off < 256; off <<= 1) {
        const unsigned tmp = (t >= off) ? s[t - off] : 0u;
        __syncthreads();
        s[t] += tmp;
        __syncthreads();
    }
    if (i < NN) part[i] = s[t] - v;            // exclusive
    if (t == 255) bsum[blockIdx.x] = s[255];
}

__global__ __launch_bounds__(512) void scan2_k(const unsigned* __restrict__ bsum,
                                               unsigned* __restrict__ bscan) {
    __shared__ unsigned s[512];
    const int t = threadIdx.x;
    const unsigned v = (t < NB1) ? bsum[t] : 0u;
    s[t] = v;
    __syncthreads();
    for (int off = 1; off < 512; off <<= 1) {
        const unsigned tmp = (t >= off) ? s[t - off] : 0u;
        __syncthreads();
        s[t] += tmp;
        __syncthreads();
    }
    if (t < NB1) bscan[t] = s[t] - v;          // exclusive
}

__global__ __launch_bounds__(256) void scan3_k(const unsigned* __restrict__ part,
                                               const unsigned* __restrict__ bscan,
                                               unsigned* __restrict__ cursor) {
    const int i = blockIdx.x * 256 + threadIdx.x;
    if (i < NN) cursor[i] = part[i] + bscan[blockIdx.x];
}

__global__ __launch_bounds__(256) void place_k(const int* __restrict__ src,
                                               const int* __restrict__ dst,
                                               const float* __restrict__ ew,
                                               unsigned* __restrict__ cursor,
                                               uint2* __restrict__ pairs) {
    const int e = blockIdx.x * 256 + threadIdx.x;   // grid covers NE exactly
    const int d = dst[e];
    const unsigned p = atomicAdd(&cursor[d], 1u);
    pairs[p] = make_uint2((unsigned)src[e], __float_as_uint(ew[e]));
}

// ---- Segment sum: one wave per node, lane = channel, NO atomics ---------
__global__ __launch_bounds__(256) void segsum_k(const float* __restrict__ h,
                                                const uint2* __restrict__ pairs,
                                                const unsigned* __restrict__ cursor,
                                                const unsigned* __restrict__ deg,
                                                float* __restrict__ hnew) {
    const int node = blockIdx.x * 4 + (threadIdx.x >> 6);   // 25000*4 == NN
    const int lane = threadIdx.x & 63;
    const unsigned end = cursor[node];
    const unsigned len = deg[node];
    const unsigned start = end - len;
    float acc = 0.0f;
    for (unsigned base = start; base < end; base += 64) {
        const int m = (int)min(64u, end - base);
        uint2 pr = make_uint2(0u, 0u);
        if (lane < m) pr = pairs[base + lane];   // coalesced 8B/lane
        #pragma unroll 4
        for (int j = 0; j < m; ++j) {
            const int   s = __shfl((int)pr.x, j);
            const float w = __shfl(__uint_as_float(pr.y), j);
            acc = fmaf(w, h[s * DD + lane], acc);   // coalesced 256B row gather
        }
    }
    hnew[node * DD + lane] = acc;
}

// ---- Weight prep: pack Wih/Whh into MFMA B-fragment order (bf16) --------
// B-frag for coltile ct (cols 16ct..16ct+15), kstep ks (k 32ks..32ks+31):
//   lane l holds col = ct*16 + (l&15), k = ks*32 + 8*(l>>4) + j (j=0..7)
//   value = W[col][k]  (B = W^T).
// Stored as wfrag[g*256 + lane*4 + (j>>1)] packing (bf16(k),bf16(k+1)).
// g = mat*24 + ct*2 + ks. Total 48KB -> L2-resident; gru_k reads each frag
// as one perfectly coalesced global_load_dwordx4 (16B/lane contiguous).
__global__ __launch_bounds__(256) void wprep_k(const float* __restrict__ Wih,
                                               const float* __restrict__ Whh,
                                               unsigned* __restrict__ wfrag) {
    const int idx = blockIdx.x * 256 + threadIdx.x;  // 24 blocks * 256 = 6144
    const int row = idx >> 5;        // W row (= output col), 0..191
    const int k2  = idx & 31;        // k/2
    const int ct  = row >> 4;
    const int c   = row & 15;
    const int ks  = k2 >> 4;
    const int lhi = (k2 >> 2) & 3;   // (k>>3)&3
    const int lane = c + (lhi << 4);
    const int slot = k2 & 3;         // (k&7)>>1
    const int fo = (((ct << 1) + ks) << 8) + (lane << 2) + slot;
    const float2 wi = *(const float2*)(Wih + (row << 6) + (k2 << 1));
    const float2 wh = *(const float2*)(Whh + (row << 6) + (k2 << 1));
    wfrag[fo]            = bf16rne(wi.x) | (bf16rne(wi.y) << 16);
    wfrag[24 * 256 + fo] = bf16rne(wh.x) | (bf16rne(wh.y) << 16);
}

// ---- GRU cell via MFMA --------------------------------------------------
// One wave per 16-node group. Two GEMMs [16,64]x[64,192] (x@Wih^T, h@Whh^T)
// as 12 coltiles x 2 ksteps of mfma_f32_16x16x32_bf16 each.
// A-frag: lane l holds row (l&15), k = ks*32 + 8*(l>>4) + j  -> two float4
// loads per matrix per kstep, converted to bf16 in-register.
// C layout (m89): col = lane&15, row = 4*(lane>>4) + reg.
// No LDS, no syncthreads. hnew aliases out: each wave reads its own 16 rows
// before writing them; groups partition rows so no cross-wave hazard.
__global__ __launch_bounds__(256) void gru_k(
    const float* hnew, const float* __restrict__ h,
    const unsigned* __restrict__ wfrag,
    const float* __restrict__ bih, const float* __restrict__ bhh,
    float* out)
{
    const int tid  = threadIdx.x;
    const int wid  = tid >> 6;
    const int lane = tid & 63;
    const int grp  = blockIdx.x * 4 + wid;
    if (grp >= NGRP) return;
    const int base = grp << 4;

    const int rA   = lane & 15;
    const int koff = (lane >> 4) << 3;

    const float* xr = hnew + ((base + rA) << 6);
    const float* hr = h    + ((base + rA) << 6);

    short8_t ax[2], ah[2];
    #pragma unroll
    for (int ks = 0; ks < 2; ++ks) {
        const float4 x0 = *(const float4*)(xr + ks * 32 + koff);
        const float4 x1 = *(const float4*)(xr + ks * 32 + koff + 4);
        const float4 h0 = *(const float4*)(hr + ks * 32 + koff);
        const float4 h1 = *(const float4*)(hr + ks * 32 + koff + 4);
        ax[ks] = pack8(x0, x1);
        ah[ks] = pack8(h0, h1);
    }

    f32x4 acc[24];
    #pragma unroll
    for (int i = 0; i < 24; ++i) acc[i] = (f32x4){0.f, 0.f, 0.f, 0.f};

    const unsigned* wf = wfrag + (lane << 2);
    #pragma unroll
    for (int ct = 0; ct < 12; ++ct) {
        const short8_t b0 = *(const short8_t*)(wf + (((ct << 1)     ) << 8));
        const short8_t b1 = *(const short8_t*)(wf + (((ct << 1) + 1) << 8));
        const short8_t c0 = *(const short8_t*)(wf + ((24 + (ct << 1)    ) << 8));
        const short8_t c1 = *(const short8_t*)(wf + ((24 + (ct << 1) + 1) << 8));
        acc[ct]      = __builtin_amdgcn_mfma_f32_16x16x32_bf16(ax[0], b0, acc[ct],      0, 0, 0);
        acc[ct]      = __builtin_amdgcn_mfma_f32_16x16x32_bf16(ax[1], b1, acc[ct],      0, 0, 0);
        acc[12 + ct] = __builtin_amdgcn_mfma_f32_16x16x32_bf16(ah[0], c0, acc[12 + ct], 0, 0, 0);
        acc[12 + ct] = __builtin_amdgcn_mfma_f32_16x16x32_bf16(ah[1], c1, acc[12 + ct], 0, 0, 0);
    }

    // Epilogue: gates r (acc 0..3 / 12..15), z (4..7 / 16..19), n (8..11 / 20..23)
    const int rnode = base + ((lane >> 4) << 2);
    const int c     = lane & 15;
    #pragma unroll
    for (int ct = 0; ct < 4; ++ct) {
        const int ch = (ct << 4) + c;
        const float brz = bih[ch] + bhh[ch];
        const float bzz = bih[64 + ch] + bhh[64 + ch];
        const float bin = bih[128 + ch];
        const float bhn = bhh[128 + ch];
        #pragma unroll
        for (int r = 0; r < 4; ++r) {
            const int node = rnode + r;
            const float rr = fsig(acc[ct][r] + acc[12 + ct][r] + brz);
            const float zz = fsig(acc[4 + ct][r] + acc[16 + ct][r] + bzz);
            const float hn = acc[20 + ct][r] + bhn;
            const float nn = ftanh(fmaf(rr, hn, acc[8 + ct][r] + bin));
            const float hv = h[(node << 6) + ch];
            out[(node << 6) + ch] = fmaf(zz, hv - nn, nn);  // (1-z)*n + z*h
        }
    }
}

extern "C" void kernel_launch(void* const* d_in, const int* in_sizes, int n_in,
                              void* d_out, int out_size, void* d_ws, size_t ws_size,
                              hipStream_t stream)
{
    const float* h   = (const float*)d_in[0];
    const float* ew  = (const float*)d_in[1];
    const float* Wih = (const float*)d_in[2];
    const float* Whh = (const float*)d_in[3];
    const float* bih = (const float*)d_in[4];
    const float* bhh = (const float*)d_in[5];
    const int*   src = (const int*)d_in[6];
    const int*   dst = (const int*)d_in[7];
    float* out = (float*)d_out;

    // ws layout (~14.05 MB, under the 25.6 MB proven available)
    char* ws = (char*)d_ws;
    unsigned* deg    = (unsigned*)(ws);                 // 400,000 B
    unsigned* cursor = (unsigned*)(ws + 400000);        // 400,000 B
    unsigned* part   = (unsigned*)(ws + 800000);        // 400,000 B
    unsigned* bsum   = (unsigned*)(ws + 1200000);       //   2,048 B
    unsigned* bscan  = (unsigned*)(ws + 1202048);       //   2,048 B
    uint2*    pairs  = (uint2*)   (ws + 1204224);       // 12.8 MB
    unsigned* wfrag  = (unsigned*)(ws + 14004224);      // 49,152 B

    hipMemsetAsync(deg, 0, NN * sizeof(unsigned), stream);
    wprep_k<<<24, 256, 0, stream>>>(Wih, Whh, wfrag);
    hist_k <<<NE / 256, 256, 0, stream>>>(dst, deg);
    scan1_k<<<NB1, 256, 0, stream>>>(deg, part, bsum);
    scan2_k<<<1, 512, 0, stream>>>(bsum, bscan);
    scan3_k<<<NB1, 256, 0, stream>>>(part, bscan, cursor);
    place_k<<<NE / 256, 256, 0, stream>>>(src, dst, ew, cursor, pairs);
    segsum_k<<<NN / 4, 256, 0, stream>>>(h, pairs, cursor, deg, out); // out = hnew
    gru_k  <<<NBGRU, 256, 0, stream>>>(out, h, wfrag, bih, bhh, out);
}